// Round 2
// baseline (574.495 us; speedup 1.0000x reference)
//
#include <hip/hip_runtime.h>
#include <math.h>

#define N_USERS 40000
#define N_ITEMS 20000
#define NNODES  60000          // N_USERS + N_ITEMS; also the zero-pad row index
#define D       128
#define N_EDGES 320000
#define EPS_    1e-7f
#define BATCH   4096
#define STRIDE  64             // ELL row capacity (max degree ~45 for Poisson(16))
#define ZSCALE  256.0f         // fp8 storage scale; folded out in bpr
#define MAX_NB  1024           // cap on persistent grid (4 blocks/CU x 256 CUs)

typedef float vf2 __attribute__((ext_vector_type(2)));

// unpack 16 fp8 (e4m3) from uint4, accumulate into 8 packed-f32 pairs.
__device__ __forceinline__ void add_fp8x16v(vf2* a, uint4 t) {
    a[0] += __builtin_amdgcn_cvt_pk_f32_fp8(t.x, false);
    a[1] += __builtin_amdgcn_cvt_pk_f32_fp8(t.x, true);
    a[2] += __builtin_amdgcn_cvt_pk_f32_fp8(t.y, false);
    a[3] += __builtin_amdgcn_cvt_pk_f32_fp8(t.y, true);
    a[4] += __builtin_amdgcn_cvt_pk_f32_fp8(t.z, false);
    a[5] += __builtin_amdgcn_cvt_pk_f32_fp8(t.z, true);
    a[6] += __builtin_amdgcn_cvt_pk_f32_fp8(t.w, false);
    a[7] += __builtin_amdgcn_cvt_pk_f32_fp8(t.w, true);
}

// scale + clamp + pack 8 vf2 (16 f32) -> 16 fp8 (e4m3) in uint4
__device__ __forceinline__ uint4 pack_fp8x16v(const vf2* a, float w) {
    float v[16];
    #pragma unroll
    for (int k = 0; k < 8; ++k) {
        v[2 * k]     = fminf(fmaxf(w * a[k].x, -448.0f), 448.0f);
        v[2 * k + 1] = fminf(fmaxf(w * a[k].y, -448.0f), 448.0f);
    }
    int w0 = __builtin_amdgcn_cvt_pk_fp8_f32(v[0],  v[1],  0,  false);
    w0     = __builtin_amdgcn_cvt_pk_fp8_f32(v[2],  v[3],  w0, true);
    int w1 = __builtin_amdgcn_cvt_pk_fp8_f32(v[4],  v[5],  0,  false);
    w1     = __builtin_amdgcn_cvt_pk_fp8_f32(v[6],  v[7],  w1, true);
    int w2 = __builtin_amdgcn_cvt_pk_fp8_f32(v[8],  v[9],  0,  false);
    w2     = __builtin_amdgcn_cvt_pk_fp8_f32(v[10], v[11], w2, true);
    int w3 = __builtin_amdgcn_cvt_pk_fp8_f32(v[12], v[13], 0,  false);
    w3     = __builtin_amdgcn_cvt_pk_fp8_f32(v[14], v[15], w3, true);
    uint4 o; o.x = (unsigned)w0; o.y = (unsigned)w1;
    o.z = (unsigned)w2; o.w = (unsigned)w3;
    return o;
}

// gather 8 padded edges (2 int4 col loads, 8 uint4 gathers all in flight)
__device__ __forceinline__ void gather8(const int4* __restrict__ rcv, int t,
                                        const uint4* __restrict__ z, int sub,
                                        vf2* a) {
    int4 ca = rcv[2 * t], cb = rcv[2 * t + 1];
    uint4 t0 = z[(ca.x << 3) + sub];
    uint4 t1 = z[(ca.y << 3) + sub];
    uint4 t2 = z[(ca.z << 3) + sub];
    uint4 t3 = z[(ca.w << 3) + sub];
    uint4 t4 = z[(cb.x << 3) + sub];
    uint4 t5 = z[(cb.y << 3) + sub];
    uint4 t6 = z[(cb.z << 3) + sub];
    uint4 t7 = z[(cb.w << 3) + sub];
    add_fp8x16v(a, t0); add_fp8x16v(a, t1);
    add_fp8x16v(a, t2); add_fp8x16v(a, t3);
    add_fp8x16v(a, t4); add_fp8x16v(a, t5);
    add_fp8x16v(a, t6); add_fp8x16v(a, t7);
}

// ---- device-wide barrier (all blocks co-resident; sized by occupancy query)
// Pattern mirrors ROCm cooperative grid.sync: release-arrive on cnt,
// acquire-spin on gen, agent scope (emits the cross-XCD wb/inv).
__device__ __forceinline__ void gbar(int* bcnt, int* bgen, int nb) {
    __syncthreads();
    if (threadIdx.x == 0) {
        __threadfence();
        int g = __hip_atomic_load(bgen, __ATOMIC_RELAXED, __HIP_MEMORY_SCOPE_AGENT);
        int a = __hip_atomic_fetch_add(bcnt, 1, __ATOMIC_ACQ_REL,
                                       __HIP_MEMORY_SCOPE_AGENT);
        if (a == nb - 1) {
            __hip_atomic_store(bcnt, 0, __ATOMIC_RELAXED, __HIP_MEMORY_SCOPE_AGENT);
            __hip_atomic_fetch_add(bgen, 1, __ATOMIC_RELEASE,
                                   __HIP_MEMORY_SCOPE_AGENT);
        } else {
            while (__hip_atomic_load(bgen, __ATOMIC_ACQUIRE,
                                     __HIP_MEMORY_SCOPE_AGENT) == g)
                __builtin_amdgcn_s_sleep(2);
        }
    }
    __syncthreads();
}

// ---- phase 1: bucketed ELL fill (int4-vectorized; fillc ends = degree) ----
// users: bucket = u/10000 (0..3); items: bucket = 4 + i/5000.
// XCD-local scatter via blockIdx&7 round-robin (R11: -30us vs naive).
__device__ __forceinline__ void fill_phase(const int4* __restrict__ au4,
                                           const int4* __restrict__ ai4,
                                           int* __restrict__ fillc,
                                           int* __restrict__ colell, int nb) {
    const int bucket = blockIdx.x & 7;
    const int stride = (nb >> 3) * 256;
    const int NE4 = N_EDGES / 4;
    for (int i = (blockIdx.x >> 3) * 256 + threadIdx.x; i < NE4; i += stride) {
        int4 us = au4[i];
        int4 is = ai4[i];
        int ua[4] = { us.x, us.y, us.z, us.w };
        int ia[4] = { is.x, is.y, is.z, is.w };
        #pragma unroll
        for (int k = 0; k < 4; ++k) {
            int u    = ua[k];
            int iraw = ia[k];
            int it   = N_USERS + iraw;
            if (u / 10000 == bucket) {
                int p = atomicAdd(&fillc[u], 1);
                if (p < STRIDE) colell[(u << 6) + p] = it;
            }
            if (4 + iraw / 5000 == bucket) {
                int p = atomicAdd(&fillc[it], 1);
                if (p < STRIDE) colell[(it << 6) + p] = u;
            }
        }
    }
}

// ---- phase 2: z0 init + colell 8-padding + shared zero-row init -----------
__device__ __forceinline__ void init_phase(const int* __restrict__ fillc,
        const float4* __restrict__ ue, const float4* __restrict__ ie,
        uint2* __restrict__ z0, uint2* __restrict__ z1, uint2* __restrict__ z2,
        int* __restrict__ colell, int nb) {
    const int total = (NNODES + 1) * 16;
    for (int i = blockIdx.x * 256 + threadIdx.x; i < total; i += nb * 256) {
        int row = i >> 4;
        int sub = i & 15;
        if (row == NNODES) {                 // zero-pad row in all three buffers
            uint2 zz = make_uint2(0u, 0u);
            z0[i] = zz; z1[i] = zz; z2[i] = zz;
            continue;
        }
        int e = fillc[row];
        if (sub == 0) {                      // pad colell row to a multiple of 8
            int ep = (e + 7) & ~7;
            for (int k = e; k < ep; ++k) colell[(row << 6) + k] = NNODES;
        }
        float w = rsqrtf((float)e + EPS_) * ZSCALE;
        float4 e0, e1;
        if (row < N_USERS) {
            int b4 = row * 32 + sub * 2;     // 32 float4 per row
            e0 = ue[b4]; e1 = ue[b4 + 1];
        } else {
            int b4 = (row - N_USERS) * 32 + sub * 2;
            e0 = ie[b4]; e1 = ie[b4 + 1];
        }
        float v[8] = { e0.x * w, e0.y * w, e0.z * w, e0.w * w,
                       e1.x * w, e1.y * w, e1.z * w, e1.w * w };
        float c[8];
        #pragma unroll
        for (int k = 0; k < 8; ++k) c[k] = fminf(fmaxf(v[k], -448.0f), 448.0f);
        int lo = __builtin_amdgcn_cvt_pk_fp8_f32(c[0], c[1], 0,  false);
        lo     = __builtin_amdgcn_cvt_pk_fp8_f32(c[2], c[3], lo, true);
        int hi = __builtin_amdgcn_cvt_pk_fp8_f32(c[4], c[5], 0,  false);
        hi     = __builtin_amdgcn_cvt_pk_fp8_f32(c[6], c[7], hi, true);
        z0[i] = make_uint2((unsigned)lo, (unsigned)hi);
    }
}

// ---- phases 3/4: SpMM, 8-lane subgroup rows, 8-edge padded chunks ---------
__device__ __forceinline__ void spmm_phase(const int* __restrict__ cnt,
        const int* __restrict__ colell, const uint4* __restrict__ z,
        uint4* __restrict__ znxt, int nb) {
    const int sub = threadIdx.x & 7;
    for (int base = blockIdx.x * 32; base < NNODES; base += nb * 32) {
        int row = base + (threadIdx.x >> 3);     // NNODES % 32 == 0
        int e = cnt[row];
        const int4* rcv = (const int4*)(colell + (row << 6));
        vf2 a[8];
        #pragma unroll
        for (int k = 0; k < 8; ++k) a[k] = (vf2)(0.0f);
        int nchunks = (e + 7) >> 3;
        for (int t = 0; t < nchunks; ++t) gather8(rcv, t, z, sub, a);
        float w = 1.0f / ((float)e + EPS_);      // dinv^2
        znxt[(row << 3) + sub] = pack_fp8x16v(a, w);
    }
}

// ---- phase 5: fused BPR loss (2 elements per wave, u/p/n 8-lane subgroups)
__device__ __forceinline__ void bpr_phase(
        const float4* __restrict__ ue, const float4* __restrict__ ie,
        const uint4* __restrict__ z1, const uint4* __restrict__ z2,
        const int* __restrict__ cnt, const int* __restrict__ colell,
        const int* __restrict__ user, const int* __restrict__ pos,
        const int* __restrict__ neg, float* __restrict__ lacc, int nb) {
    __shared__ float s[8];
    if (threadIdx.x < 8) s[threadIdx.x] = 0.0f;
    __syncthreads();
    const int lane = threadIdx.x & 63;
    const int sg   = lane >> 3;
    const int sub  = lane & 7;
    const int half = sg >> 2;            // 0 = elem A, 1 = elem B
    const int sgl  = sg & 3;             // 0=u 1=p 2=n 3=idle
    float lsum = 0.0f;
    for (int w = blockIdx.x * 4 + (int)(threadIdx.x >> 6); w < BATCH / 2;
         w += nb * 4) {
        int el = w * 2 + half;
        int u = user[el];
        int p = N_USERS + pos[el] - 1;   // 1-indexed items
        int n = N_USERS + neg[el] - 1;
        int node = (sgl == 1) ? p : (sgl == 2) ? n : u;
        float cnode = 0.0f;
        vf2 vals[8];
        #pragma unroll
        for (int k = 0; k < 8; ++k) vals[k] = (vf2)(0.0f);
        if (sgl < 3) {
            int e = cnt[node];
            cnode = (float)e;
            // layer-0 exact from f32 embeddings: 4 float4 per lane
            const float4* eb = (node < N_USERS) ? ue : ie;
            int b4 = ((node < N_USERS) ? node : node - N_USERS) * 32 + sub * 4;
            float4 e0 = eb[b4], e1 = eb[b4 + 1], e2 = eb[b4 + 2], e3 = eb[b4 + 3];
            float w0 = rsqrtf(cnode + EPS_) * ZSCALE;
            vals[0] = (vf2){w0 * e0.x, w0 * e0.y}; vals[1] = (vf2){w0 * e0.z, w0 * e0.w};
            vals[2] = (vf2){w0 * e1.x, w0 * e1.y}; vals[3] = (vf2){w0 * e1.z, w0 * e1.w};
            vals[4] = (vf2){w0 * e2.x, w0 * e2.y}; vals[5] = (vf2){w0 * e2.z, w0 * e2.w};
            vals[6] = (vf2){w0 * e3.x, w0 * e3.y}; vals[7] = (vf2){w0 * e3.z, w0 * e3.w};
            int o = (node << 3) + sub;
            add_fp8x16v(vals, z1[o]);
            add_fp8x16v(vals, z2[o]);
            // inline layer-3 gather from z2 (f32), 8-edge padded chunks
            const int4* rcv = (const int4*)(colell + (node << 6));
            vf2 a[8];
            #pragma unroll
            for (int k = 0; k < 8; ++k) a[k] = (vf2)(0.0f);
            int nchunks = (e + 7) >> 3;
            for (int t = 0; t < nchunks; ++t) gather8(rcv, t, z2, sub, a);
            float w2 = 1.0f / (cnode + EPS_);   // dinv^2
            #pragma unroll
            for (int k = 0; k < 8; ++k) vals[k] += w2 * a[k];
        }
        // pull the u-subgroup (sg0 / sg4) values into all subgroups of the half
        int usrc = sub | (lane & 32);
        float dotp = 0.0f;
        #pragma unroll
        for (int k = 0; k < 8; ++k) {
            dotp += __shfl(vals[k].x, usrc) * vals[k].x;
            dotp += __shfl(vals[k].y, usrc) * vals[k].y;
        }
        dotp += __shfl_down(dotp, 4, 8);
        dotp += __shfl_down(dotp, 2, 8);
        dotp += __shfl_down(dotp, 1, 8);
        // subgroup heads now hold: lane (lane&32)+8 -> u.p, +16 -> u.n
        float sp = __shfl(dotp, (lane & 32) + 8);
        float sn = __shfl(dotp, (lane & 32) + 16);
        float cu = __shfl(cnode, (lane & 32) + 0);
        float cp = __shfl(cnode, (lane & 32) + 8);
        float cn = __shfl(cnode, (lane & 32) + 16);
        if ((lane & 31) == 0) {   // lane 0 (elem A) and lane 32 (elem B)
            float du = rsqrtf(cu + EPS_), dp = rsqrtf(cp + EPS_), dn = rsqrtf(cn + EPS_);
            const float inv = 1.0f / (16.0f * ZSCALE * ZSCALE);
            float diff = (sp / (du * dp) - sn / (du * dn)) * inv;
            // log_sigmoid(x) = min(x,0) - log1p(exp(-|x|))
            lsum += fminf(diff, 0.0f) - log1pf(expf(-fabsf(diff)));
        }
    }
    if ((lane & 31) == 0) s[(threadIdx.x >> 6) * 2 + half] = lsum;
    __syncthreads();
    if (threadIdx.x == 0) {
        float t = s[0] + s[1] + s[2] + s[3] + s[4] + s[5] + s[6] + s[7];
        atomicAdd(lacc, t);
    }
}

// ---- single persistent mega-kernel: fill -> init -> L1 -> L2 -> bpr -------
__global__ void __launch_bounds__(256)
lightgcn_mega(const float4* ue, const float4* ie,
              const int* au, const int* ai,
              const int* user, const int* pos, const int* neg,
              uint4* z0, uint4* z1, uint4* z2,
              int* fillc, int* colell, float* lacc,
              int* bcnt, int* bgen, float* out, int nb) {
    fill_phase((const int4*)au, (const int4*)ai, fillc, colell, nb);
    gbar(bcnt, bgen, nb);
    init_phase(fillc, ue, ie, (uint2*)z0, (uint2*)z1, (uint2*)z2, colell, nb);
    gbar(bcnt, bgen, nb);
    spmm_phase(fillc, colell, z0, z1, nb);
    gbar(bcnt, bgen, nb);
    spmm_phase(fillc, colell, z1, z2, nb);
    gbar(bcnt, bgen, nb);
    bpr_phase(ue, ie, z1, z2, fillc, colell, user, pos, neg, lacc, nb);
    gbar(bcnt, bgen, nb);
    if (blockIdx.x == 0 && threadIdx.x == 0) {
        float total = __hip_atomic_load(lacc, __ATOMIC_RELAXED,
                                        __HIP_MEMORY_SCOPE_AGENT);
        out[0] = -total * (1.0f / (float)BATCH);
    }
}

extern "C" void kernel_launch(void* const* d_in, const int* in_sizes, int n_in,
                              void* d_out, int out_size, void* d_ws, size_t ws_size,
                              hipStream_t stream) {
    const float* ue  = (const float*)d_in[0];
    const float* ie  = (const float*)d_in[1];
    const int*   au  = (const int*)d_in[2];
    const int*   ai  = (const int*)d_in[3];
    const int*   usr = (const int*)d_in[4];
    const int*   pos = (const int*)d_in[5];
    const int*   neg = (const int*)d_in[6];
    float*       out = (float*)d_out;

    const size_t ZQ4 = (size_t)(NNODES + 1) * 8;  // uint4 per z buffer (+zero row)

    // ws layout (16B-aligned chunks):
    // z0 | z1 | z2 (fp8, NNODES+1 rows) | [fillc | lacc | bcnt | bgen] | colell
    uint4* z0     = (uint4*)d_ws;
    uint4* z1     = z0 + ZQ4;
    uint4* z2     = z1 + ZQ4;
    int*   fillc  = (int*)(z2 + ZQ4);
    float* lacc   = (float*)(fillc + NNODES);
    int*   bcnt   = (int*)(lacc + 1);
    int*   bgen   = bcnt + 1;
    int*   colell = (int*)(lacc + 4);             // NNODES * STRIDE ints

    // persistent grid: guaranteed co-resident (deadlock-free barrier),
    // multiple of 8 to preserve the XCD bucket mapping in fill_phase.
    static int nb = 0;
    if (nb == 0) {
        int mob = 0;
        hipError_t err = hipOccupancyMaxActiveBlocksPerMultiprocessor(
            &mob, lightgcn_mega, 256, 0);
        long t;
        if (err != hipSuccess || mob <= 0) {
            // conservative fallback: 1 block/CU is always co-resident
            t = 256;
        } else {
            hipDeviceProp_t prop;
            int dev = 0;
            (void)hipGetDevice(&dev);
            if (hipGetDeviceProperties(&prop, dev) == hipSuccess)
                t = (long)mob * (long)prop.multiProcessorCount;
            else
                t = 256;
        }
        if (t > MAX_NB) t = MAX_NB;
        t &= ~7L;
        if (t < 8) t = 8;
        nb = (int)t;
    }

    // fillc + lacc + barrier state zeroed in one shot (ws is re-poisoned
    // between iterations, so this must cover bcnt/bgen every launch)
    hipMemsetAsync(fillc, 0, (NNODES + 4) * sizeof(int), stream);

    lightgcn_mega<<<nb, 256, 0, stream>>>(
        (const float4*)ue, (const float4*)ie, au, ai, usr, pos, neg,
        z0, z1, z2, fillc, colell, lacc, bcnt, bgen, out, nb);
}

// Round 3
// 273.284 us; speedup vs baseline: 2.1022x; 2.1022x over previous
//
#include <hip/hip_runtime.h>
#include <math.h>

#define N_USERS 40000
#define N_ITEMS 20000
#define NNODES  60000          // N_USERS + N_ITEMS; also the zero-pad row index
#define D       128
#define N_EDGES 320000
#define EPS_    1e-7f
#define BATCH   4096
#define STRIDE  64             // ELL row capacity (max degree ~45 for Poisson(16))
#define ZSCALE  256.0f         // fp8 storage scale; folded out in bpr
#define MAX_NB  1024           // cap on persistent grid (4 blocks/CU x 256 CUs)

typedef float vf2 __attribute__((ext_vector_type(2)));

// unpack 16 fp8 (e4m3) from uint4, accumulate into 8 packed-f32 pairs.
__device__ __forceinline__ void add_fp8x16v(vf2* a, uint4 t) {
    a[0] += __builtin_amdgcn_cvt_pk_f32_fp8(t.x, false);
    a[1] += __builtin_amdgcn_cvt_pk_f32_fp8(t.x, true);
    a[2] += __builtin_amdgcn_cvt_pk_f32_fp8(t.y, false);
    a[3] += __builtin_amdgcn_cvt_pk_f32_fp8(t.y, true);
    a[4] += __builtin_amdgcn_cvt_pk_f32_fp8(t.z, false);
    a[5] += __builtin_amdgcn_cvt_pk_f32_fp8(t.z, true);
    a[6] += __builtin_amdgcn_cvt_pk_f32_fp8(t.w, false);
    a[7] += __builtin_amdgcn_cvt_pk_f32_fp8(t.w, true);
}

// scale + clamp + pack 8 vf2 (16 f32) -> 16 fp8 (e4m3) in uint4
__device__ __forceinline__ uint4 pack_fp8x16v(const vf2* a, float w) {
    float v[16];
    #pragma unroll
    for (int k = 0; k < 8; ++k) {
        v[2 * k]     = fminf(fmaxf(w * a[k].x, -448.0f), 448.0f);
        v[2 * k + 1] = fminf(fmaxf(w * a[k].y, -448.0f), 448.0f);
    }
    int w0 = __builtin_amdgcn_cvt_pk_fp8_f32(v[0],  v[1],  0,  false);
    w0     = __builtin_amdgcn_cvt_pk_fp8_f32(v[2],  v[3],  w0, true);
    int w1 = __builtin_amdgcn_cvt_pk_fp8_f32(v[4],  v[5],  0,  false);
    w1     = __builtin_amdgcn_cvt_pk_fp8_f32(v[6],  v[7],  w1, true);
    int w2 = __builtin_amdgcn_cvt_pk_fp8_f32(v[8],  v[9],  0,  false);
    w2     = __builtin_amdgcn_cvt_pk_fp8_f32(v[10], v[11], w2, true);
    int w3 = __builtin_amdgcn_cvt_pk_fp8_f32(v[12], v[13], 0,  false);
    w3     = __builtin_amdgcn_cvt_pk_fp8_f32(v[14], v[15], w3, true);
    uint4 o; o.x = (unsigned)w0; o.y = (unsigned)w1;
    o.z = (unsigned)w2; o.w = (unsigned)w3;
    return o;
}

// gather 8 padded edges (2 int4 col loads, 8 uint4 gathers all in flight)
__device__ __forceinline__ void gather8(const int4* __restrict__ rcv, int t,
                                        const uint4* __restrict__ z, int sub,
                                        vf2* a) {
    int4 ca = rcv[2 * t], cb = rcv[2 * t + 1];
    uint4 t0 = z[(ca.x << 3) + sub];
    uint4 t1 = z[(ca.y << 3) + sub];
    uint4 t2 = z[(ca.z << 3) + sub];
    uint4 t3 = z[(ca.w << 3) + sub];
    uint4 t4 = z[(cb.x << 3) + sub];
    uint4 t5 = z[(cb.y << 3) + sub];
    uint4 t6 = z[(cb.z << 3) + sub];
    uint4 t7 = z[(cb.w << 3) + sub];
    add_fp8x16v(a, t0); add_fp8x16v(a, t1);
    add_fp8x16v(a, t2); add_fp8x16v(a, t3);
    add_fp8x16v(a, t4); add_fp8x16v(a, t5);
    add_fp8x16v(a, t6); add_fp8x16v(a, t7);
}

// ---- device-wide barrier, generation g = 0,1,2,... ------------------------
// R2 lesson: ACQUIRE-per-poll at agent scope = buffer_inv storm (1 ms, 1.9%
// VALUBusy). Correct recipe: cache maintenance exactly twice per block
// (one producer __threadfence = L2 wb, one consumer __threadfence = inv);
// the spin itself uses RELAXED atomic loads (no cache ops, served at the
// coherence point). Two-level monotonic arrive cuts same-line atomic
// serialization 8x. Monotonic counters need no per-generation reset.
__device__ __forceinline__ void gbar(int g, int* __restrict__ c8,
                                     int* __restrict__ fcnt,
                                     int* __restrict__ bgen, int nb) {
    __syncthreads();
    if (threadIdx.x == 0) {
        __threadfence();                          // producer: wb dirty L2
        const int nbx = nb >> 3;
        int* cme = c8 + ((blockIdx.x & 7) << 5);  // 128B-spaced counters
        int a = __hip_atomic_fetch_add(cme, 1, __ATOMIC_RELAXED,
                                       __HIP_MEMORY_SCOPE_AGENT);
        if (a == nbx * (g + 1) - 1) {             // last arrival of my slot
            int f = __hip_atomic_fetch_add(fcnt, 1, __ATOMIC_RELAXED,
                                           __HIP_MEMORY_SCOPE_AGENT);
            if (f == 8 * (g + 1) - 1)             // last slot overall
                __hip_atomic_fetch_add(bgen, 1, __ATOMIC_RELEASE,
                                       __HIP_MEMORY_SCOPE_AGENT);
        }
        while (__hip_atomic_load(bgen, __ATOMIC_RELAXED,
                                 __HIP_MEMORY_SCOPE_AGENT) <= g)
            __builtin_amdgcn_s_sleep(4);
        __threadfence();                          // consumer: inv L1/L2 once
    }
    __syncthreads();
}

// ---- phase 1: bucketed ELL fill (int4-vectorized; fillc ends = degree) ----
// users: bucket = u/10000 (0..3); items: bucket = 4 + i/5000.
// XCD-local scatter via blockIdx&7 round-robin (R11: -30us vs naive).
__device__ __forceinline__ void fill_phase(const int4* __restrict__ au4,
                                           const int4* __restrict__ ai4,
                                           int* __restrict__ fillc,
                                           int* __restrict__ colell, int nb) {
    const int bucket = blockIdx.x & 7;
    const int stride = (nb >> 3) * 256;
    const int NE4 = N_EDGES / 4;
    for (int i = (blockIdx.x >> 3) * 256 + threadIdx.x; i < NE4; i += stride) {
        int4 us = au4[i];
        int4 is = ai4[i];
        int ua[4] = { us.x, us.y, us.z, us.w };
        int ia[4] = { is.x, is.y, is.z, is.w };
        #pragma unroll
        for (int k = 0; k < 4; ++k) {
            int u    = ua[k];
            int iraw = ia[k];
            int it   = N_USERS + iraw;
            if (u / 10000 == bucket) {
                int p = atomicAdd(&fillc[u], 1);
                if (p < STRIDE) colell[(u << 6) + p] = it;
            }
            if (4 + iraw / 5000 == bucket) {
                int p = atomicAdd(&fillc[it], 1);
                if (p < STRIDE) colell[(it << 6) + p] = u;
            }
        }
    }
}

// ---- phase 2: z0 init + colell 8-padding + shared zero-row init -----------
__device__ __forceinline__ void init_phase(const int* __restrict__ fillc,
        const float4* __restrict__ ue, const float4* __restrict__ ie,
        uint2* __restrict__ z0, uint2* __restrict__ z1, uint2* __restrict__ z2,
        int* __restrict__ colell, int nb) {
    const int total = (NNODES + 1) * 16;
    for (int i = blockIdx.x * 256 + threadIdx.x; i < total; i += nb * 256) {
        int row = i >> 4;
        int sub = i & 15;
        if (row == NNODES) {                 // zero-pad row in all three buffers
            uint2 zz = make_uint2(0u, 0u);
            z0[i] = zz; z1[i] = zz; z2[i] = zz;
            continue;
        }
        int e = fillc[row];
        if (sub == 0) {                      // pad colell row to a multiple of 8
            int ep = (e + 7) & ~7;
            for (int k = e; k < ep; ++k) colell[(row << 6) + k] = NNODES;
        }
        float w = rsqrtf((float)e + EPS_) * ZSCALE;
        float4 e0, e1;
        if (row < N_USERS) {
            int b4 = row * 32 + sub * 2;     // 32 float4 per row
            e0 = ue[b4]; e1 = ue[b4 + 1];
        } else {
            int b4 = (row - N_USERS) * 32 + sub * 2;
            e0 = ie[b4]; e1 = ie[b4 + 1];
        }
        float v[8] = { e0.x * w, e0.y * w, e0.z * w, e0.w * w,
                       e1.x * w, e1.y * w, e1.z * w, e1.w * w };
        float c[8];
        #pragma unroll
        for (int k = 0; k < 8; ++k) c[k] = fminf(fmaxf(v[k], -448.0f), 448.0f);
        int lo = __builtin_amdgcn_cvt_pk_fp8_f32(c[0], c[1], 0,  false);
        lo     = __builtin_amdgcn_cvt_pk_fp8_f32(c[2], c[3], lo, true);
        int hi = __builtin_amdgcn_cvt_pk_fp8_f32(c[4], c[5], 0,  false);
        hi     = __builtin_amdgcn_cvt_pk_fp8_f32(c[6], c[7], hi, true);
        z0[i] = make_uint2((unsigned)lo, (unsigned)hi);
    }
}

// ---- phases 3/4: SpMM, 8-lane subgroup rows, 8-edge padded chunks ---------
__device__ __forceinline__ void spmm_phase(const int* __restrict__ cnt,
        const int* __restrict__ colell, const uint4* __restrict__ z,
        uint4* __restrict__ znxt, int nb) {
    const int sub = threadIdx.x & 7;
    for (int base = blockIdx.x * 32; base < NNODES; base += nb * 32) {
        int row = base + (threadIdx.x >> 3);     // NNODES % 32 == 0
        int e = cnt[row];
        const int4* rcv = (const int4*)(colell + (row << 6));
        vf2 a[8];
        #pragma unroll
        for (int k = 0; k < 8; ++k) a[k] = (vf2)(0.0f);
        int nchunks = (e + 7) >> 3;
        for (int t = 0; t < nchunks; ++t) gather8(rcv, t, z, sub, a);
        float w = 1.0f / ((float)e + EPS_);      // dinv^2
        znxt[(row << 3) + sub] = pack_fp8x16v(a, w);
    }
}

// ---- phase 5: fused BPR loss (2 elements per wave, u/p/n 8-lane subgroups)
__device__ __forceinline__ void bpr_phase(
        const float4* __restrict__ ue, const float4* __restrict__ ie,
        const uint4* __restrict__ z1, const uint4* __restrict__ z2,
        const int* __restrict__ cnt, const int* __restrict__ colell,
        const int* __restrict__ user, const int* __restrict__ pos,
        const int* __restrict__ neg, float* __restrict__ lacc, int nb) {
    __shared__ float s[8];
    if (threadIdx.x < 8) s[threadIdx.x] = 0.0f;
    __syncthreads();
    const int lane = threadIdx.x & 63;
    const int sg   = lane >> 3;
    const int sub  = lane & 7;
    const int half = sg >> 2;            // 0 = elem A, 1 = elem B
    const int sgl  = sg & 3;             // 0=u 1=p 2=n 3=idle
    float lsum = 0.0f;
    for (int w = blockIdx.x * 4 + (int)(threadIdx.x >> 6); w < BATCH / 2;
         w += nb * 4) {
        int el = w * 2 + half;
        int u = user[el];
        int p = N_USERS + pos[el] - 1;   // 1-indexed items
        int n = N_USERS + neg[el] - 1;
        int node = (sgl == 1) ? p : (sgl == 2) ? n : u;
        float cnode = 0.0f;
        vf2 vals[8];
        #pragma unroll
        for (int k = 0; k < 8; ++k) vals[k] = (vf2)(0.0f);
        if (sgl < 3) {
            int e = cnt[node];
            cnode = (float)e;
            // layer-0 exact from f32 embeddings: 4 float4 per lane
            const float4* eb = (node < N_USERS) ? ue : ie;
            int b4 = ((node < N_USERS) ? node : node - N_USERS) * 32 + sub * 4;
            float4 e0 = eb[b4], e1 = eb[b4 + 1], e2 = eb[b4 + 2], e3 = eb[b4 + 3];
            float w0 = rsqrtf(cnode + EPS_) * ZSCALE;
            vals[0] = (vf2){w0 * e0.x, w0 * e0.y}; vals[1] = (vf2){w0 * e0.z, w0 * e0.w};
            vals[2] = (vf2){w0 * e1.x, w0 * e1.y}; vals[3] = (vf2){w0 * e1.z, w0 * e1.w};
            vals[4] = (vf2){w0 * e2.x, w0 * e2.y}; vals[5] = (vf2){w0 * e2.z, w0 * e2.w};
            vals[6] = (vf2){w0 * e3.x, w0 * e3.y}; vals[7] = (vf2){w0 * e3.z, w0 * e3.w};
            int o = (node << 3) + sub;
            add_fp8x16v(vals, z1[o]);
            add_fp8x16v(vals, z2[o]);
            // inline layer-3 gather from z2 (f32), 8-edge padded chunks
            const int4* rcv = (const int4*)(colell + (node << 6));
            vf2 a[8];
            #pragma unroll
            for (int k = 0; k < 8; ++k) a[k] = (vf2)(0.0f);
            int nchunks = (e + 7) >> 3;
            for (int t = 0; t < nchunks; ++t) gather8(rcv, t, z2, sub, a);
            float w2 = 1.0f / (cnode + EPS_);   // dinv^2
            #pragma unroll
            for (int k = 0; k < 8; ++k) vals[k] += w2 * a[k];
        }
        // pull the u-subgroup (sg0 / sg4) values into all subgroups of the half
        int usrc = sub | (lane & 32);
        float dotp = 0.0f;
        #pragma unroll
        for (int k = 0; k < 8; ++k) {
            dotp += __shfl(vals[k].x, usrc) * vals[k].x;
            dotp += __shfl(vals[k].y, usrc) * vals[k].y;
        }
        dotp += __shfl_down(dotp, 4, 8);
        dotp += __shfl_down(dotp, 2, 8);
        dotp += __shfl_down(dotp, 1, 8);
        // subgroup heads now hold: lane (lane&32)+8 -> u.p, +16 -> u.n
        float sp = __shfl(dotp, (lane & 32) + 8);
        float sn = __shfl(dotp, (lane & 32) + 16);
        float cu = __shfl(cnode, (lane & 32) + 0);
        float cp = __shfl(cnode, (lane & 32) + 8);
        float cn = __shfl(cnode, (lane & 32) + 16);
        if ((lane & 31) == 0) {   // lane 0 (elem A) and lane 32 (elem B)
            float du = rsqrtf(cu + EPS_), dp = rsqrtf(cp + EPS_), dn = rsqrtf(cn + EPS_);
            const float inv = 1.0f / (16.0f * ZSCALE * ZSCALE);
            float diff = (sp / (du * dp) - sn / (du * dn)) * inv;
            // log_sigmoid(x) = min(x,0) - log1p(exp(-|x|))
            lsum += fminf(diff, 0.0f) - log1pf(expf(-fabsf(diff)));
        }
    }
    if ((lane & 31) == 0) s[(threadIdx.x >> 6) * 2 + half] = lsum;
    __syncthreads();
    if (threadIdx.x == 0) {
        float t = s[0] + s[1] + s[2] + s[3] + s[4] + s[5] + s[6] + s[7];
        atomicAdd(lacc, t);
    }
}

// ---- single persistent mega-kernel: fill -> init -> L1 -> L2 -> bpr -------
__global__ void __launch_bounds__(256)
lightgcn_mega(const float4* ue, const float4* ie,
              const int* au, const int* ai,
              const int* user, const int* pos, const int* neg,
              uint4* z0, uint4* z1, uint4* z2,
              int* fillc, int* colell, float* lacc,
              int* c8, int* fcnt, int* bgen, float* out, int nb) {
    fill_phase((const int4*)au, (const int4*)ai, fillc, colell, nb);
    gbar(0, c8, fcnt, bgen, nb);
    init_phase(fillc, ue, ie, (uint2*)z0, (uint2*)z1, (uint2*)z2, colell, nb);
    gbar(1, c8, fcnt, bgen, nb);
    spmm_phase(fillc, colell, z0, z1, nb);
    gbar(2, c8, fcnt, bgen, nb);
    spmm_phase(fillc, colell, z1, z2, nb);
    gbar(3, c8, fcnt, bgen, nb);
    bpr_phase(ue, ie, z1, z2, fillc, colell, user, pos, neg, lacc, nb);
    gbar(4, c8, fcnt, bgen, nb);
    if (blockIdx.x == 0 && threadIdx.x == 0) {
        float total = __hip_atomic_load(lacc, __ATOMIC_RELAXED,
                                        __HIP_MEMORY_SCOPE_AGENT);
        out[0] = -total * (1.0f / (float)BATCH);
    }
}

extern "C" void kernel_launch(void* const* d_in, const int* in_sizes, int n_in,
                              void* d_out, int out_size, void* d_ws, size_t ws_size,
                              hipStream_t stream) {
    const float* ue  = (const float*)d_in[0];
    const float* ie  = (const float*)d_in[1];
    const int*   au  = (const int*)d_in[2];
    const int*   ai  = (const int*)d_in[3];
    const int*   usr = (const int*)d_in[4];
    const int*   pos = (const int*)d_in[5];
    const int*   neg = (const int*)d_in[6];
    float*       out = (float*)d_out;

    const size_t ZQ4 = (size_t)(NNODES + 1) * 8;  // uint4 per z buffer (+zero row)

    // ws layout (16B-aligned chunks):
    // z0 | z1 | z2 | [fillc | c8[256] | fcnt | bgen | lacc | pad] | colell
    uint4* z0     = (uint4*)d_ws;
    uint4* z1     = z0 + ZQ4;
    uint4* z2     = z1 + ZQ4;
    int*   fillc  = (int*)(z2 + ZQ4);
    int*   c8     = fillc + NNODES;               // 8 slots x 32 ints (128B)
    int*   fcnt   = c8 + 256;
    int*   bgen   = fcnt + 1;
    float* lacc   = (float*)(bgen + 1);
    int*   colell = (int*)(lacc + 2);             // byte off 241040, 16B-aligned

    // persistent grid: guaranteed co-resident (deadlock-free barrier),
    // multiple of 8 to preserve the XCD bucket mapping + barrier slots.
    static int nb = 0;
    if (nb == 0) {
        int mob = 0;
        hipError_t err = hipOccupancyMaxActiveBlocksPerMultiprocessor(
            &mob, lightgcn_mega, 256, 0);
        long t;
        if (err != hipSuccess || mob <= 0) {
            t = 256;                              // 1 block/CU always resident
        } else {
            hipDeviceProp_t prop;
            int dev = 0;
            (void)hipGetDevice(&dev);
            if (hipGetDeviceProperties(&prop, dev) == hipSuccess)
                t = (long)mob * (long)prop.multiProcessorCount;
            else
                t = 256;
        }
        if (t > MAX_NB) t = MAX_NB;
        t &= ~7L;
        if (t < 8) t = 8;
        nb = (int)t;
    }

    // fillc + c8 + fcnt + bgen + lacc zeroed in one shot (ws re-poisoned
    // between iterations, so barrier state must be re-zeroed every launch)
    hipMemsetAsync(fillc, 0, (NNODES + 256 + 4) * sizeof(int), stream);

    lightgcn_mega<<<nb, 256, 0, stream>>>(
        (const float4*)ue, (const float4*)ie, au, ai, usr, pos, neg,
        z0, z1, z2, fillc, colell, lacc, c8, fcnt, bgen, out, nb);
}

// Round 7
// 168.107 us; speedup vs baseline: 3.4174x; 1.6257x over previous
//
#include <hip/hip_runtime.h>
#include <math.h>

#define N_USERS 40000
#define N_ITEMS 20000
#define NNODES  60000          // N_USERS + N_ITEMS; also the zero-pad row index
#define D       128
#define N_EDGES 320000
#define EPS_    1e-7f
#define BATCH   4096
#define STRIDE  64             // ELL row capacity (max degree ~45 for Poisson(16))
#define ZSCALE  256.0f         // fp8 storage scale; folded out in bpr
#define BPR_BLOCKS (BATCH / 8)             // 512: 4 waves x 2 elements each
#define FILL_GRPS  320                     // blocks per bucket
#define FILL_BLOCKS (8 * FILL_GRPS)        // 2560
#define INIT_BLOCKS (((NNODES + 1) * 16 + 255) / 256)  // 3751 (16 thr/row, +pad row)
#define FULL_BLOCKS (NNODES * 8 / 256)     // 1875 (8 threads per row)

typedef float vf2 __attribute__((ext_vector_type(2)));
typedef unsigned u32x2 __attribute__((ext_vector_type(2)));
typedef unsigned u32x4 __attribute__((ext_vector_type(4)));
typedef float    f32x4 __attribute__((ext_vector_type(4)));

// non-temporal (stream, no-L2-allocate) access: z buffers are consumed by
// random-XCD readers (1/8 local-hit chance), so keeping them out of the
// writer's L2 preserves residency for colell/edges and trims the
// end-of-kernel dirty-writeback on the critical path. (R3 lesson: the
// inter-phase flush is per-kernel-boundary and unavoidable; minimize what
// it has to write back.) NT builtins need native ext_vector types, not
// HIP_vector_type structs (R4 compile fail) -> cast through aliases.
__device__ __forceinline__ void nts_u2(uint2* p, uint2 v) {
    u32x2 t; t.x = v.x; t.y = v.y;
    __builtin_nontemporal_store(t, (u32x2*)p);
}
__device__ __forceinline__ void nts_u4(uint4* p, uint4 v) {
    u32x4 t; t.x = v.x; t.y = v.y; t.z = v.z; t.w = v.w;
    __builtin_nontemporal_store(t, (u32x4*)p);
}
__device__ __forceinline__ float4 ntl_f4(const float4* p) {
    f32x4 t = __builtin_nontemporal_load((const f32x4*)p);
    return make_float4(t.x, t.y, t.z, t.w);
}

// unpack 16 fp8 (e4m3) from uint4, accumulate into 8 packed-f32 pairs.
__device__ __forceinline__ void add_fp8x16v(vf2* a, uint4 t) {
    a[0] += __builtin_amdgcn_cvt_pk_f32_fp8(t.x, false);
    a[1] += __builtin_amdgcn_cvt_pk_f32_fp8(t.x, true);
    a[2] += __builtin_amdgcn_cvt_pk_f32_fp8(t.y, false);
    a[3] += __builtin_amdgcn_cvt_pk_f32_fp8(t.y, true);
    a[4] += __builtin_amdgcn_cvt_pk_f32_fp8(t.z, false);
    a[5] += __builtin_amdgcn_cvt_pk_f32_fp8(t.z, true);
    a[6] += __builtin_amdgcn_cvt_pk_f32_fp8(t.w, false);
    a[7] += __builtin_amdgcn_cvt_pk_f32_fp8(t.w, true);
}

// scale + clamp + pack 8 vf2 (16 f32) -> 16 fp8 (e4m3) in uint4
__device__ __forceinline__ uint4 pack_fp8x16v(const vf2* a, float w) {
    float v[16];
    #pragma unroll
    for (int k = 0; k < 8; ++k) {
        v[2 * k]     = fminf(fmaxf(w * a[k].x, -448.0f), 448.0f);
        v[2 * k + 1] = fminf(fmaxf(w * a[k].y, -448.0f), 448.0f);
    }
    int w0 = __builtin_amdgcn_cvt_pk_fp8_f32(v[0],  v[1],  0,  false);
    w0     = __builtin_amdgcn_cvt_pk_fp8_f32(v[2],  v[3],  w0, true);
    int w1 = __builtin_amdgcn_cvt_pk_fp8_f32(v[4],  v[5],  0,  false);
    w1     = __builtin_amdgcn_cvt_pk_fp8_f32(v[6],  v[7],  w1, true);
    int w2 = __builtin_amdgcn_cvt_pk_fp8_f32(v[8],  v[9],  0,  false);
    w2     = __builtin_amdgcn_cvt_pk_fp8_f32(v[10], v[11], w2, true);
    int w3 = __builtin_amdgcn_cvt_pk_fp8_f32(v[12], v[13], 0,  false);
    w3     = __builtin_amdgcn_cvt_pk_fp8_f32(v[14], v[15], w3, true);
    uint4 o; o.x = (unsigned)w0; o.y = (unsigned)w1;
    o.z = (unsigned)w2; o.w = (unsigned)w3;
    return o;
}

// gather 8 padded edges (2 int4 col loads, 8 uint4 gathers all in flight)
__device__ __forceinline__ void gather8(const int4* __restrict__ rcv, int t,
                                        const uint4* __restrict__ z, int sub,
                                        vf2* a) {
    int4 ca = rcv[2 * t], cb = rcv[2 * t + 1];
    uint4 t0 = z[(ca.x << 3) + sub];
    uint4 t1 = z[(ca.y << 3) + sub];
    uint4 t2 = z[(ca.z << 3) + sub];
    uint4 t3 = z[(ca.w << 3) + sub];
    uint4 t4 = z[(cb.x << 3) + sub];
    uint4 t5 = z[(cb.y << 3) + sub];
    uint4 t6 = z[(cb.z << 3) + sub];
    uint4 t7 = z[(cb.w << 3) + sub];
    add_fp8x16v(a, t0); add_fp8x16v(a, t1);
    add_fp8x16v(a, t2); add_fp8x16v(a, t3);
    add_fp8x16v(a, t4); add_fp8x16v(a, t5);
    add_fp8x16v(a, t6); add_fp8x16v(a, t7);
}

// ---- bucketed ELL fill (int4-vectorized); fillc ends holding the degree --
// users: bucket = u/10000 (0..3); items: bucket = 4 + i/5000.
// XCD-local scatter writes via blockIdx&7 round-robin (R11: -30us vs naive).
// int4 scan verified correct in mega rounds R2/R3 (absmax 0).
__global__ void fill_ell(const int4* __restrict__ au4, const int4* __restrict__ ai4,
                         int* __restrict__ fillc, int* __restrict__ colell) {
    const int bucket = blockIdx.x & 7;
    const int grp    = blockIdx.x >> 3;          // 0..FILL_GRPS-1
    const int NE4    = N_EDGES / 4;
    for (int i = grp * 256 + threadIdx.x; i < NE4; i += FILL_GRPS * 256) {
        int4 us = au4[i];
        int4 is = ai4[i];
        int ua[4] = { us.x, us.y, us.z, us.w };
        int ia[4] = { is.x, is.y, is.z, is.w };
        #pragma unroll
        for (int k = 0; k < 4; ++k) {
            int u    = ua[k];
            int iraw = ia[k];
            int it   = N_USERS + iraw;
            if (u / 10000 == bucket) {
                int p = atomicAdd(&fillc[u], 1);
                if (p < STRIDE) colell[(u << 6) + p] = it;
            }
            if (4 + iraw / 5000 == bucket) {
                int p = atomicAdd(&fillc[it], 1);
                if (p < STRIDE) colell[(it << 6) + p] = u;
            }
        }
    }
}

// ---- z0 init + colell 8-padding + zero-row init --------------------------
// 16 threads per row. Row NNODES is the shared zero row of z0/z1/z2.
__global__ void init_z(const int* __restrict__ fillc,
                       const float4* __restrict__ ue, const float4* __restrict__ ie,
                       uint2* __restrict__ z0, uint2* __restrict__ z1,
                       uint2* __restrict__ z2, int* __restrict__ colell) {
    int i   = blockIdx.x * 256 + threadIdx.x;
    if (i >= (NNODES + 1) * 16) return;
    int row = i >> 4;
    int sub = i & 15;
    if (row == NNODES) {                 // zero-pad row in all three buffers
        uint2 zz = make_uint2(0u, 0u);
        nts_u2(&z0[i], zz); nts_u2(&z1[i], zz); nts_u2(&z2[i], zz);
        return;
    }
    int e = fillc[row];
    if (sub == 0) {                      // pad colell row to a multiple of 8
        int ep = (e + 7) & ~7;
        for (int k = e; k < ep; ++k) colell[(row << 6) + k] = NNODES;
    }
    float w = rsqrtf((float)e + EPS_) * ZSCALE;
    float4 e0, e1;
    if (row < N_USERS) {
        int b4 = row * 32 + sub * 2;     // 32 float4 per row
        e0 = ntl_f4(&ue[b4]); e1 = ntl_f4(&ue[b4 + 1]);
    } else {
        int b4 = (row - N_USERS) * 32 + sub * 2;
        e0 = ntl_f4(&ie[b4]); e1 = ntl_f4(&ie[b4 + 1]);
    }
    float v[8] = { e0.x * w, e0.y * w, e0.z * w, e0.w * w,
                   e1.x * w, e1.y * w, e1.z * w, e1.w * w };
    float c[8];
    #pragma unroll
    for (int k = 0; k < 8; ++k) c[k] = fminf(fmaxf(v[k], -448.0f), 448.0f);
    int lo = __builtin_amdgcn_cvt_pk_fp8_f32(c[0], c[1], 0,  false);
    lo     = __builtin_amdgcn_cvt_pk_fp8_f32(c[2], c[3], lo, true);
    int hi = __builtin_amdgcn_cvt_pk_fp8_f32(c[4], c[5], 0,  false);
    hi     = __builtin_amdgcn_cvt_pk_fp8_f32(c[6], c[7], hi, true);
    nts_u2(&z0[i], make_uint2((unsigned)lo, (unsigned)hi));
}

// ---- SpMM, 8-lane subgroup rows, 8-edge padded chunks (mixed rows) -------
// R15 showed mixed-row single dispatch beats bipartite phase-split: the
// gather is transaction-rate bound; maximal grid co-scheduling wins.
__device__ __forceinline__ void spmm_body(const int* __restrict__ cnt,
                                          const int* __restrict__ colell,
                                          const uint4* __restrict__ z,
                                          uint4* __restrict__ znxt) {
    int tid = blockIdx.x * 256 + threadIdx.x;
    int row = tid >> 3;               // 32 rows per 256-thread block
    int sub = threadIdx.x & 7;
    int e = cnt[row];
    const int4* rcv = (const int4*)(colell + (row << 6));
    vf2 a[8];
    #pragma unroll
    for (int k = 0; k < 8; ++k) a[k] = (vf2)(0.0f);
    int nchunks = (e + 7) >> 3;
    for (int t = 0; t < nchunks; ++t) gather8(rcv, t, z, sub, a);
    float w = 1.0f / ((float)e + EPS_);   // dinv^2
    nts_u4(&znxt[(row << 3) + sub], pack_fp8x16v(a, w));
}

__global__ void spmm_L1(const int* __restrict__ cnt, const int* __restrict__ colell,
                        const uint4* __restrict__ z, uint4* __restrict__ znxt) {
    spmm_body(cnt, colell, z, znxt);
}
__global__ void spmm_L2(const int* __restrict__ cnt, const int* __restrict__ colell,
                        const uint4* __restrict__ z, uint4* __restrict__ znxt) {
    spmm_body(cnt, colell, z, znxt);
}

// ---- fused BPR loss: 2 elements per wave; u/p/n rows in 8-lane subgroups
// sg 0-2 = elem A's u/p/n, sg 4-6 = elem B's; sg 3/7 idle.
// zsum = dinv*ZSCALE*emb (f32 exact) + z1 + z2 + inline layer-3 from z2.
// diff = (sp/(du*dp) - sn/(du*dn)) / (16 * ZSCALE^2)
__global__ void bpr_loss(const float4* __restrict__ ue, const float4* __restrict__ ie,
                         const uint4* __restrict__ z1, const uint4* __restrict__ z2,
                         const int* __restrict__ cnt, const int* __restrict__ colell,
                         const int* __restrict__ user, const int* __restrict__ pos,
                         const int* __restrict__ neg,
                         float* __restrict__ lacc, int* __restrict__ done,
                         float* __restrict__ out) {
    __shared__ float s[8];
    int wave = (blockIdx.x * 256 + threadIdx.x) >> 6;   // global wave id
    int lane = threadIdx.x & 63;
    int sg   = lane >> 3;          // 0..7
    int sub  = lane & 7;
    int half = sg >> 2;            // 0 = elem A, 1 = elem B
    int sgl  = sg & 3;             // 0=u 1=p 2=n 3=idle
    int el   = wave * 2 + half;
    int u = user[el];
    int p = N_USERS + pos[el] - 1;  // 1-indexed items
    int n = N_USERS + neg[el] - 1;
    int node = (sgl == 1) ? p : (sgl == 2) ? n : u;
    float cnode = 0.0f;
    vf2 vals[8];
    #pragma unroll
    for (int k = 0; k < 8; ++k) vals[k] = (vf2)(0.0f);
    if (sgl < 3) {
        int e = cnt[node];
        cnode = (float)e;
        // layer-0 exact from f32 embeddings: 4 float4 per lane
        const float4* eb = (node < N_USERS) ? ue : ie;
        int b4 = ((node < N_USERS) ? node : node - N_USERS) * 32 + sub * 4;
        float4 e0 = eb[b4], e1 = eb[b4 + 1], e2 = eb[b4 + 2], e3 = eb[b4 + 3];
        float w0 = rsqrtf(cnode + EPS_) * ZSCALE;
        vals[0] = (vf2){w0 * e0.x, w0 * e0.y}; vals[1] = (vf2){w0 * e0.z, w0 * e0.w};
        vals[2] = (vf2){w0 * e1.x, w0 * e1.y}; vals[3] = (vf2){w0 * e1.z, w0 * e1.w};
        vals[4] = (vf2){w0 * e2.x, w0 * e2.y}; vals[5] = (vf2){w0 * e2.z, w0 * e2.w};
        vals[6] = (vf2){w0 * e3.x, w0 * e3.y}; vals[7] = (vf2){w0 * e3.z, w0 * e3.w};
        int o = (node << 3) + sub;
        add_fp8x16v(vals, z1[o]);
        add_fp8x16v(vals, z2[o]);
        // inline layer-3 gather from z2 (f32), 8-edge padded chunks
        const int4* rcv = (const int4*)(colell + (node << 6));
        vf2 a[8];
        #pragma unroll
        for (int k = 0; k < 8; ++k) a[k] = (vf2)(0.0f);
        int nchunks = (e + 7) >> 3;
        for (int t = 0; t < nchunks; ++t) gather8(rcv, t, z2, sub, a);
        float w2 = 1.0f / (cnode + EPS_);   // dinv^2
        #pragma unroll
        for (int k = 0; k < 8; ++k) vals[k] += w2 * a[k];
    }
    // pull the u-subgroup (sg0 / sg4) values into all subgroups of the half
    int usrc = sub | (lane & 32);
    float dotp = 0.0f;
    #pragma unroll
    for (int k = 0; k < 8; ++k) {
        dotp += __shfl(vals[k].x, usrc) * vals[k].x;
        dotp += __shfl(vals[k].y, usrc) * vals[k].y;
    }
    dotp += __shfl_down(dotp, 4, 8);
    dotp += __shfl_down(dotp, 2, 8);
    dotp += __shfl_down(dotp, 1, 8);
    // subgroup heads now hold: lane (lane&32)+8 -> u.p, +16 -> u.n
    float sp = __shfl(dotp, (lane & 32) + 8);
    float sn = __shfl(dotp, (lane & 32) + 16);
    float cu = __shfl(cnode, (lane & 32) + 0);
    float cp = __shfl(cnode, (lane & 32) + 8);
    float cn = __shfl(cnode, (lane & 32) + 16);
    if ((lane & 31) == 0) {   // lane 0 (elem A) and lane 32 (elem B)
        float du = rsqrtf(cu + EPS_), dp = rsqrtf(cp + EPS_), dn = rsqrtf(cn + EPS_);
        const float inv = 1.0f / (16.0f * ZSCALE * ZSCALE);
        float diff = (sp / (du * dp) - sn / (du * dn)) * inv;
        // log_sigmoid(x) = min(x,0) - log1p(exp(-|x|))
        s[(threadIdx.x >> 6) * 2 + half] =
            fminf(diff, 0.0f) - log1pf(expf(-fabsf(diff)));
    }
    __syncthreads();
    if (threadIdx.x == 0) {
        float t = s[0] + s[1] + s[2] + s[3] + s[4] + s[5] + s[6] + s[7];
        atomicAdd(lacc, t);
        __threadfence();
        int prev = atomicAdd(done, 1);
        if (prev == BPR_BLOCKS - 1) {
            float total = atomicAdd(lacc, 0.0f);   // coherent read
            out[0] = -total * (1.0f / (float)BATCH);
        }
    }
}

extern "C" void kernel_launch(void* const* d_in, const int* in_sizes, int n_in,
                              void* d_out, int out_size, void* d_ws, size_t ws_size,
                              hipStream_t stream) {
    const float* ue  = (const float*)d_in[0];
    const float* ie  = (const float*)d_in[1];
    const int*   au  = (const int*)d_in[2];
    const int*   ai  = (const int*)d_in[3];
    const int*   usr = (const int*)d_in[4];
    const int*   pos = (const int*)d_in[5];
    const int*   neg = (const int*)d_in[6];
    float*       out = (float*)d_out;

    const size_t ZQ4 = (size_t)(NNODES + 1) * 8;  // uint4 per z buffer (+zero row)

    // ws layout (16B-aligned chunks):
    // z0 | z1 | z2 (fp8, NNODES+1 rows) | [fillc | lacc | done | pad] | colell
    uint4* z0     = (uint4*)d_ws;
    uint4* z1     = z0 + ZQ4;
    uint4* z2     = z1 + ZQ4;
    int*   fillc  = (int*)(z2 + ZQ4);
    float* lacc   = (float*)(fillc + NNODES);
    int*   done   = (int*)(lacc + 1);
    int*   colell = (int*)(lacc + 4);             // NNODES * STRIDE ints

    // fillc + lacc + done zeroed in one shot
    hipMemsetAsync(fillc, 0, (NNODES + 4) * sizeof(int), stream);

    fill_ell<<<FILL_BLOCKS, 256, 0, stream>>>((const int4*)au, (const int4*)ai,
                                              fillc, colell);
    init_z<<<INIT_BLOCKS, 256, 0, stream>>>(fillc, (const float4*)ue,
                                            (const float4*)ie, (uint2*)z0,
                                            (uint2*)z1, (uint2*)z2, colell);

    spmm_L1<<<FULL_BLOCKS, 256, 0, stream>>>(fillc, colell, z0, z1);
    spmm_L2<<<FULL_BLOCKS, 256, 0, stream>>>(fillc, colell, z1, z2);

    bpr_loss<<<BPR_BLOCKS, 256, 0, stream>>>((const float4*)ue, (const float4*)ie,
                                             z1, z2, fillc, colell,
                                             usr, pos, neg, lacc, done, out);
}